// Round 5
// baseline (810.636 us; speedup 1.0000x reference)
//
#include <hip/hip_runtime.h>
#include <math.h>

// Heatmap: out[b,j,r,c] = exp(-((r - ceil(y))^2 + (c - ceil(x))^2) / 3)
// H = W = 64, N_JOINTS = 21, B = 2048. Output f32 = 672 MiB -> write-BW bound.
//
// ROUND 5 = RERUN of round-4 MEASUREMENT PROBE (round 4 = acquisition
// timeout, no data). Kernel launched TWICE (idempotent writes).
// dur_us_new - dur_us_round3(677) = one kernel's true duration K, since the
// harness's poison fills dominate the timed region and hide our dispatch
// from the top-5 counter rows.  K ~= 115us -> at write roofline; K ~= 227us
// -> store path investigation next.

typedef float f32x4 __attribute__((ext_vector_type(4)));

__global__ __launch_bounds__(256) void heatmap_kernel(
    const float* __restrict__ x, float* __restrict__ out, int nbj) {
    const int t  = threadIdx.x;              // 0..255
    const int c0 = (t & 15) * 4;             // column group
    const int r0 = t >> 4;                   // base row 0..15

    constexpr float k = -0.48089834696298783f;  // -(1/3) * log2(e)

    const float2* __restrict__ xx = (const float2*)x;

    int bj = blockIdx.x;
    if (bj >= nbj) return;
    float2 p = xx[bj];

    while (true) {
        const int bj_next = bj + gridDim.x;
        const bool has_next = bj_next < nbj;
        float2 pn = p;
        if (has_next) pn = xx[bj_next];      // prefetch next map's keypoint

        const float px = ceilf(p.x);
        const float py = ceilf(p.y);

        const float d0 = (float)(c0 + 0) - px;
        const float d1 = (float)(c0 + 1) - px;
        const float d2 = (float)(c0 + 2) - px;
        const float d3 = (float)(c0 + 3) - px;
        const float cfx = exp2f(d0 * d0 * k);
        const float cfy = exp2f(d1 * d1 * k);
        const float cfz = exp2f(d2 * d2 * k);
        const float cfw = exp2f(d3 * d3 * k);

        f32x4* __restrict__ outv = (f32x4*)(out + (size_t)bj * 4096);

#pragma unroll
        for (int j = 0; j < 4; ++j) {
            const float dr = (float)(j * 16 + r0) - py;
            const float rf = exp2f(dr * dr * k);
            f32x4 v;
            v.x = rf * cfx;
            v.y = rf * cfy;
            v.z = rf * cfz;
            v.w = rf * cfw;
            __builtin_nontemporal_store(v, &outv[j * 256 + t]);
        }

        if (!has_next) break;
        bj = bj_next;
        p = pn;
    }
}

extern "C" void kernel_launch(void* const* d_in, const int* in_sizes, int n_in,
                              void* d_out, int out_size, void* d_ws, size_t ws_size,
                              hipStream_t stream) {
    const float* x = (const float*)d_in[0];
    float* out = (float*)d_out;
    const int nbj = in_sizes[0] / 2;  // 2048 * 21 = 43008
    const int grid = nbj < 2048 ? nbj : 2048;  // 8 blocks/CU, 21 maps/block
    // PROBE: two identical launches; delta vs round 3 isolates one kernel's K.
    heatmap_kernel<<<grid, 256, 0, stream>>>(x, out, nbj);
    heatmap_kernel<<<grid, 256, 0, stream>>>(x, out, nbj);
}